// Round 1
// baseline (387.182 us; speedup 1.0000x reference)
//
#include <hip/hip_runtime.h>
#include <math.h>

#define B_ 2
#define S_ 128
#define H_ 4
#define DK_ 128
#define NB_ 4
#define D_ 512
#define M_ 256   // B_*S_

// ---------------------------------------------------------------------------
// ws layout (float offsets)
//  qkv   : 6 * M_*D_ = 786432   @ 0        (q1,k1,v1,q2,k2,v2, each [256,512])
//  pq    : 131072               @ 786432
//  pk    : 131072               @ 917504
//  bbq   : 16384                @ 1048576  ([B,NB,NB,D])
//  bbk   : 16384                @ 1064960
//  fQm   : 524288               @ 1081344  ([B,H,S,NB,DK])
//  fQs   : 524288               @ 1605632
//  fKm   : 524288               @ 2129920  ([B,H,NB,S,DK])
//  fKs   : 524288               @ 2654208
//  mctx  : 131072               @ 3178496  ([B,S,D])
//  cctx  : 131072               @ 3309568
//  wmT   : 262144               @ 3440640  (mean_w transposed)
//  wcT   : 262144               @ 3702784
//  total : 3964928 floats = 15.86 MB
// ---------------------------------------------------------------------------

// ① q1,k1,v1 (o=0..2) and q2,k2,v2 with elu+1 (o=3..5).
//   out[o][m, d'] = sum_d A1[m,d]*W1[d,d'] + A2[m,d]*W2[d,d']
__global__ __launch_bounds__(256) void k_proj(
    const float* __restrict__ x_m, const float* __restrict__ x_c,
    const float* __restrict__ b_m, const float* __restrict__ b_c,
    const float* __restrict__ W_xm, const float* __restrict__ W_xc,
    const float* __restrict__ W_bm, const float* __restrict__ W_bc,
    float* __restrict__ qkv)
{
    const int o = blockIdx.y;            // 0..5
    const int rowtile = blockIdx.x & 15; // 16 tiles x 16 rows
    const int strip = blockIdx.x >> 4;   // 0..1 (256-col halves)
    const int t = threadIdx.x;
    const int dp = strip * 256 + t;
    const int m0 = rowtile * 16;

    const float* A1 = (o < 3) ? x_m : x_c;
    const float* A2 = (o < 3) ? b_m : b_c;
    const float* W1 = ((o < 3) ? W_xm : W_xc) + (o % 3) * (D_ * D_);
    const float* W2 = ((o < 3) ? W_bm : W_bc) + (o % 3) * (D_ * D_);

    __shared__ float a1[16][64];
    __shared__ float a2[16][64];

    float acc[16];
#pragma unroll
    for (int r = 0; r < 16; ++r) acc[r] = 0.f;

    for (int k0 = 0; k0 < D_; k0 += 64) {
        __syncthreads();
#pragma unroll
        for (int u = 0; u < 4; ++u) {
            int e = u * 256 + t;
            int r = e >> 6, kk = e & 63;
            a1[r][kk] = A1[(m0 + r) * D_ + k0 + kk];
            a2[r][kk] = A2[(m0 + r) * D_ + k0 + kk];
        }
        __syncthreads();
        const float* w1p = W1 + k0 * D_ + dp;
        const float* w2p = W2 + k0 * D_ + dp;
#pragma unroll 4
        for (int kk = 0; kk < 64; ++kk) {
            float w1 = w1p[kk * D_];
            float w2 = w2p[kk * D_];
#pragma unroll
            for (int r = 0; r < 16; ++r)
                acc[r] = fmaf(a1[r][kk], w1, fmaf(a2[r][kk], w2, acc[r]));
        }
    }

    float* dst = qkv + o * (M_ * D_);
#pragma unroll
    for (int r = 0; r < 16; ++r) {
        float v = acc[r];
        if (o >= 3) v = (v > 0.f) ? (v + 1.f) : __expf(v);  // elu(x)+1
        dst[(m0 + r) * D_ + dp] = v;
    }
}

// ② per-head 128x128 lins: pq=lin(pm,Wq2), pk=lin(pm,Wk2), bbq=lin(bbm,Wq1), bbk=lin(bbm,Wk1)
//   rows flattened so src/dst offset = row*128.  out[k] = sum_k' p[k']*W[k,k'] + b[k]
__global__ __launch_bounds__(128) void k_lin(
    const float* __restrict__ p_m, const float* __restrict__ bb_m,
    const float* __restrict__ Wq2, const float* __restrict__ bq2,
    const float* __restrict__ Wk2, const float* __restrict__ bk2,
    const float* __restrict__ Wq1, const float* __restrict__ bq1,
    const float* __restrict__ Wk1, const float* __restrict__ bk1,
    float* __restrict__ pq, float* __restrict__ pk,
    float* __restrict__ bbq, float* __restrict__ bbk)
{
    const int bx = blockIdx.x, t = threadIdx.x;
    const float *src, *Wm, *bias;
    float* dst;
    int row0;
    if (bx < 128)      { src = p_m;  Wm = Wq2; bias = bq2; dst = pq;  row0 = bx * 8; }
    else if (bx < 256) { src = p_m;  Wm = Wk2; bias = bk2; dst = pk;  row0 = (bx - 128) * 8; }
    else if (bx < 272) { src = bb_m; Wm = Wq1; bias = bq1; dst = bbq; row0 = (bx - 256) * 8; }
    else               { src = bb_m; Wm = Wk1; bias = bk1; dst = bbk; row0 = (bx - 272) * 8; }

    __shared__ float ps[8][128];
    __shared__ float wsh[128][33];

#pragma unroll
    for (int r = 0; r < 8; ++r) ps[r][t] = src[(row0 + r) * 128 + t];

    float acc[8];
#pragma unroll
    for (int r = 0; r < 8; ++r) acc[r] = 0.f;

    const int kc = t & 31, kr0 = t >> 5;
    for (int c0 = 0; c0 < 128; c0 += 32) {
        __syncthreads();
#pragma unroll 8
        for (int u = 0; u < 32; ++u)
            wsh[kr0 + u * 4][kc] = Wm[(kr0 + u * 4) * 128 + c0 + kc];
        __syncthreads();
#pragma unroll 8
        for (int k2 = 0; k2 < 32; ++k2) {
            float wv = wsh[t][k2];
#pragma unroll
            for (int r = 0; r < 8; ++r)
                acc[r] = fmaf(ps[r][c0 + k2], wv, acc[r]);
        }
    }

    float bv = bias[t];
#pragma unroll
    for (int r = 0; r < 8; ++r) dst[(row0 + r) * 128 + t] = acc[r] + bv;
}

// ③ transpose mean_w/cov_w (512x512), z selects matrix
__global__ __launch_bounds__(256) void k_transpose(
    const float* __restrict__ mean_w, const float* __restrict__ cov_w,
    float* __restrict__ wmT, float* __restrict__ wcT)
{
    const float* src = blockIdx.z ? cov_w : mean_w;
    float* dst = blockIdx.z ? wcT : wmT;
    __shared__ float tile[32][33];
    const int tx = threadIdx.x & 31, ty = threadIdx.x >> 5;
    const int bx = blockIdx.x, by = blockIdx.y;
#pragma unroll
    for (int u = 0; u < 4; ++u)
        tile[ty + u * 8][tx] = src[(by * 32 + ty + u * 8) * 512 + bx * 32 + tx];
    __syncthreads();
#pragma unroll
    for (int u = 0; u < 4; ++u)
        dst[(bx * 32 + ty + u * 8) * 512 + by * 32 + tx] = tile[tx][ty + u * 8];
}

// ④ tri-SAGP fuse: side=0 → fQ(i, sj) for sj=0..3 ; side=1 → fK(si, j) for si=0..3
__global__ __launch_bounds__(128) void k_fuse(
    const float* __restrict__ qkv, const float* __restrict__ pq,
    const float* __restrict__ pk, const float* __restrict__ bbq,
    const float* __restrict__ bbk, const float* __restrict__ bb_c,
    const float* __restrict__ p_c, const int* __restrict__ b_seq,
    float* __restrict__ fQm, float* __restrict__ fQs,
    float* __restrict__ fKm, float* __restrict__ fKs)
{
    const int t = threadIdx.x;
    const int ij = blockIdx.x;      // i (side 0) or j (side 1)
    const int h = blockIdx.y;
    const int b = blockIdx.z >> 1;
    const int side = blockIdx.z & 1;
    const int d = h * 128 + t;
    const float eps = 1e-24f;
    const int base = (b * S_ + ij) * D_ + d;
    const int s_self = b_seq[b * S_ + ij];

    float m1, c1, m3;
    if (side == 0) { m1 = qkv[base]; c1 = qkv[3 * M_ * D_ + base]; m3 = pq[base]; }
    else           { m1 = qkv[M_ * D_ + base]; c1 = qkv[4 * M_ * D_ + base]; m3 = pk[base]; }
    float c3 = p_c[base];

    float p1 = 1.f / fmaxf(c1, eps);
    float p3 = 1.f / fmaxf(c3, eps);
    float mp13 = m1 * p1 + m3 * p3;
    const float* bbM = side ? bbk : bbq;

#pragma unroll
    for (int sv = 0; sv < 4; ++sv) {
        int n1 = side ? s_self : sv;   // table first index = seq[j]
        int n2 = side ? sv : s_self;   // table second index = seq[i]
        int idx = (b * 16 + n1 * 4 + n2) * 512 + d;
        float m2 = bbM[idx];
        float c2 = bb_c[idx];
        float p2 = 1.f / fmaxf(c2, eps);
        float cc = 1.f / (p1 + p2 + p3);
        float fm = cc * (mp13 + m2 * p2);
        float fs = sqrtf(fmaxf(cc, eps));
        if (side == 0) {
            int o = ((b * H_ + h) * S_ + ij) * 512 + sv * 128 + t;   // [B,H,S,NB,DK]
            fQm[o] = fm; fQs[o] = fs;
        } else {
            int o = (((b * H_ + h) * 4 + sv) * S_ + ij) * 128 + t;   // [B,H,NB,S,DK]
            fKm[o] = fm; fKs[o] = fs;
        }
    }
}

// ⑤ per (b,h,i): W2 distances, softmax, probs out, mean/cov ctx
__global__ __launch_bounds__(128) void k_attn(
    const float* __restrict__ fQm, const float* __restrict__ fQs,
    const float* __restrict__ fKm, const float* __restrict__ fKs,
    const float* __restrict__ qkv, const int* __restrict__ b_seq,
    float* __restrict__ probs_out, float* __restrict__ mctx,
    float* __restrict__ cctx)
{
    const int t = threadIdx.x;     // j, later k
    const int i = blockIdx.x, h = blockIdx.y, b = blockIdx.z;

    __shared__ __attribute__((aligned(16))) float qm[4 * 132];
    __shared__ __attribute__((aligned(16))) float qs[4 * 132];
    __shared__ float red[4];
    __shared__ float pr[128], pr2[128];

    const int si = b_seq[b * S_ + i];
    const int sj = b_seq[b * S_ + t];
    const int qbase = ((b * H_ + h) * S_ + i) * 512;
#pragma unroll
    for (int u = 0; u < 4; ++u) {
        qm[u * 132 + t] = fQm[qbase + u * 128 + t];
        qs[u * 132 + t] = fQs[qbase + u * 128 + t];
    }
    __syncthreads();

    const int krow = (((b * H_ + h) * 4 + si) * S_ + t) * 128;
    const float4* kmp = (const float4*)(fKm + krow);
    const float4* ksp = (const float4*)(fKs + krow);

    float w2 = 0.f;
#pragma unroll 4
    for (int k4 = 0; k4 < 32; ++k4) {
        float4 km = kmp[k4];
        float4 ks = ksp[k4];
        float4 m = *(const float4*)&qm[sj * 132 + k4 * 4];
        float4 s = *(const float4*)&qs[sj * 132 + k4 * 4];
        float d0 = m.x - km.x, d1 = m.y - km.y, d2 = m.z - km.z, d3 = m.w - km.w;
        float e0 = s.x - ks.x, e1 = s.y - ks.y, e2 = s.z - ks.z, e3 = s.w - ks.w;
        w2 += d0 * d0 + d1 * d1 + d2 * d2 + d3 * d3
            + e0 * e0 + e1 * e1 + e2 * e2 + e3 * e3;
    }
    float score = -w2 * 0.08838834764831845f;  // 1/sqrt(128)

    // softmax over 128 threads (2 waves)
    float mx = score;
#pragma unroll
    for (int off = 32; off >= 1; off >>= 1) mx = fmaxf(mx, __shfl_xor(mx, off));
    if ((t & 63) == 0) red[t >> 6] = mx;
    __syncthreads();
    mx = fmaxf(red[0], red[1]);
    float e = __expf(score - mx);
    float sm = e;
#pragma unroll
    for (int off = 32; off >= 1; off >>= 1) sm += __shfl_xor(sm, off);
    if ((t & 63) == 0) red[2 + (t >> 6)] = sm;
    __syncthreads();
    float p = e / (red[2] + red[3]);

    probs_out[((b * H_ + h) * S_ + i) * S_ + t] = p;
    pr[t] = p;
    pr2[t] = p * p;
    __syncthreads();

    // ctx: thread t = k
    const float* v1 = qkv + 2 * M_ * D_ + (b * S_) * D_ + h * 128 + t;
    const float* v2 = qkv + 5 * M_ * D_ + (b * S_) * D_ + h * 128 + t;
    float am = 0.f, ac = 0.f;
#pragma unroll 8
    for (int j = 0; j < 128; ++j) {
        am = fmaf(pr[j], v1[j * D_], am);
        ac = fmaf(pr2[j], v2[j * D_], ac);
    }
    mctx[(b * S_ + i) * D_ + h * 128 + t] = am;
    cctx[(b * S_ + i) * D_ + h * 128 + t] = ac;
}

// ⑥ epilogue: y = ctx @ W^T + bias + residual; LN; write mean_h / cov_h
__global__ __launch_bounds__(256) void k_final(
    const float* __restrict__ mctx, const float* __restrict__ cctx,
    const float* __restrict__ wmT, const float* __restrict__ wcT,
    const float* __restrict__ mean_b, const float* __restrict__ cov_b,
    const float* __restrict__ x_m, const float* __restrict__ x_c,
    const float* __restrict__ ln_w, const float* __restrict__ ln_b,
    float* __restrict__ out)
{
    const int t = threadIdx.x;
    const int r0 = blockIdx.x * 2;
    const int d0 = t, d1 = t + 256;

    __shared__ float cm[2][512], ccv[2][512];
    __shared__ float red[8];

#pragma unroll
    for (int u = 0; u < 4; ++u) {
        int e = u * 256 + t;
        int r = e >> 9, dd = e & 511;
        cm[r][dd] = mctx[(r0 + r) * 512 + dd];
        ccv[r][dd] = cctx[(r0 + r) * 512 + dd];
    }
    __syncthreads();

    float am[2][2] = {{0.f, 0.f}, {0.f, 0.f}};
    float av[2][2] = {{0.f, 0.f}, {0.f, 0.f}};
#pragma unroll 4
    for (int d = 0; d < 512; ++d) {
        float w0 = wmT[d * 512 + d0], w1 = wmT[d * 512 + d1];
        float v0 = wcT[d * 512 + d0], v1 = wcT[d * 512 + d1];
        float a0 = cm[0][d], a1 = cm[1][d];
        float b0 = ccv[0][d], b1 = ccv[1][d];
        am[0][0] = fmaf(a0, w0, am[0][0]); am[0][1] = fmaf(a0, w1, am[0][1]);
        am[1][0] = fmaf(a1, w0, am[1][0]); am[1][1] = fmaf(a1, w1, am[1][1]);
        av[0][0] = fmaf(b0, v0, av[0][0]); av[0][1] = fmaf(b0, v1, av[0][1]);
        av[1][0] = fmaf(b1, v0, av[1][0]); av[1][1] = fmaf(b1, v1, av[1][1]);
    }

    const float lw0 = ln_w[d0], lw1 = ln_w[d1], lb0 = ln_b[d0], lb1 = ln_b[d1];

#pragma unroll
    for (int r = 0; r < 2; ++r) {
        const int row = r0 + r;
        // ---- mean output ----
        {
            float y0 = am[r][0] + mean_b[d0] + x_m[row * 512 + d0];
            float y1 = am[r][1] + mean_b[d1] + x_m[row * 512 + d1];
            float s = y0 + y1, ss = y0 * y0 + y1 * y1;
#pragma unroll
            for (int off = 32; off >= 1; off >>= 1) { s += __shfl_xor(s, off); ss += __shfl_xor(ss, off); }
            if ((t & 63) == 0) { red[t >> 6] = s; red[4 + (t >> 6)] = ss; }
            __syncthreads();
            float mu = (red[0] + red[1] + red[2] + red[3]) * (1.f / 512.f);
            float var = (red[4] + red[5] + red[6] + red[7]) * (1.f / 512.f) - mu * mu;
            float rstd = 1.f / sqrtf(var + 1e-12f);
            out[row * 512 + d0] = (y0 - mu) * rstd * lw0 + lb0;
            out[row * 512 + d1] = (y1 - mu) * rstd * lw1 + lb1;
            __syncthreads();
        }
        // ---- cov output ----
        {
            float y0 = av[r][0] + cov_b[d0] + x_c[row * 512 + d0];
            float y1 = av[r][1] + cov_b[d1] + x_c[row * 512 + d1];
            float s = y0 + y1, ss = y0 * y0 + y1 * y1;
#pragma unroll
            for (int off = 32; off >= 1; off >>= 1) { s += __shfl_xor(s, off); ss += __shfl_xor(ss, off); }
            if ((t & 63) == 0) { red[t >> 6] = s; red[4 + (t >> 6)] = ss; }
            __syncthreads();
            float mu = (red[0] + red[1] + red[2] + red[3]) * (1.f / 512.f);
            float var = (red[4] + red[5] + red[6] + red[7]) * (1.f / 512.f) - mu * mu;
            float rstd = 1.f / sqrtf(var + 1e-12f);
            out[131072 + row * 512 + d0] = (y0 - mu) * rstd * lw0 + lb0;
            out[131072 + row * 512 + d1] = (y1 - mu) * rstd * lw1 + lb1;
            __syncthreads();
        }
    }
}

extern "C" void kernel_launch(void* const* d_in, const int* in_sizes, int n_in,
                              void* d_out, int out_size, void* d_ws, size_t ws_size,
                              hipStream_t stream) {
    (void)in_sizes; (void)n_in; (void)out_size; (void)ws_size;
    const float* x_m   = (const float*)d_in[0];
    const float* x_c   = (const float*)d_in[1];
    const float* b_m   = (const float*)d_in[2];
    const float* b_c   = (const float*)d_in[3];
    const float* bb_m  = (const float*)d_in[4];
    const float* bb_c  = (const float*)d_in[5];
    const float* p_m   = (const float*)d_in[6];
    const float* p_c   = (const float*)d_in[7];
    const float* W_xm  = (const float*)d_in[8];
    const float* W_xc  = (const float*)d_in[9];
    const float* W_bm  = (const float*)d_in[10];
    const float* W_bc  = (const float*)d_in[11];
    const float* Wq1_w = (const float*)d_in[12];
    const float* Wq1_b = (const float*)d_in[13];
    const float* Wq2_w = (const float*)d_in[14];
    const float* Wq2_b = (const float*)d_in[15];
    const float* Wk1_w = (const float*)d_in[16];
    const float* Wk1_b = (const float*)d_in[17];
    const float* Wk2_w = (const float*)d_in[18];
    const float* Wk2_b = (const float*)d_in[19];
    const float* mean_w = (const float*)d_in[20];
    const float* mean_b = (const float*)d_in[21];
    const float* cov_w  = (const float*)d_in[22];
    const float* cov_b  = (const float*)d_in[23];
    const float* ln_w   = (const float*)d_in[24];
    const float* ln_b   = (const float*)d_in[25];
    const int*   b_seq  = (const int*)d_in[26];

    float* ws   = (float*)d_ws;
    float* qkv  = ws;
    float* pq   = ws + 786432;
    float* pk   = ws + 917504;
    float* bbq  = ws + 1048576;
    float* bbk  = ws + 1064960;
    float* fQm  = ws + 1081344;
    float* fQs  = ws + 1605632;
    float* fKm  = ws + 2129920;
    float* fKs  = ws + 2654208;
    float* mctx = ws + 3178496;
    float* cctx = ws + 3309568;
    float* wmT  = ws + 3440640;
    float* wcT  = ws + 3702784;
    float* out  = (float*)d_out;

    k_proj<<<dim3(32, 6), 256, 0, stream>>>(x_m, x_c, b_m, b_c, W_xm, W_xc, W_bm, W_bc, qkv);
    k_lin<<<dim3(288), 128, 0, stream>>>(p_m, bb_m, Wq2_w, Wq2_b, Wk2_w, Wk2_b,
                                         Wq1_w, Wq1_b, Wk1_w, Wk1_b, pq, pk, bbq, bbk);
    k_transpose<<<dim3(16, 16, 2), 256, 0, stream>>>(mean_w, cov_w, wmT, wcT);
    k_fuse<<<dim3(128, 4, 4), 128, 0, stream>>>(qkv, pq, pk, bbq, bbk, bb_c, p_c, b_seq,
                                                fQm, fQs, fKm, fKs);
    k_attn<<<dim3(128, 4, 2), 128, 0, stream>>>(fQm, fQs, fKm, fKs, qkv, b_seq,
                                                out + 262144, mctx, cctx);
    k_final<<<dim3(128), 256, 0, stream>>>(mctx, cctx, wmT, wcT, mean_b, cov_b,
                                           x_m, x_c, ln_w, ln_b, out);
}

// Round 2
// 309.963 us; speedup vs baseline: 1.2491x; 1.2491x over previous
//
#include <hip/hip_runtime.h>
#include <math.h>

#define B_ 2
#define S_ 128
#define H_ 4
#define DK_ 128
#define NB_ 4
#define D_ 512
#define M_ 256   // B_*S_

__device__ __forceinline__ float elu1(float x) {
    return (x > 0.f) ? (x + 1.f) : __expf(x);
}

// ---------------------------------------------------------------------------
// ws layout (float offsets)
//  qkv   : 6 * M_*D_ = 786432   @ 0        (q1,k1,v1,q2raw,k2raw,v2, each [256,512])
//  pq    : 131072               @ 786432
//  pk    : 131072               @ 917504
//  bbq   : 16384                @ 1048576  ([B,NB,NB,D])
//  bbk   : 16384                @ 1064960
//  fQm   : 524288               @ 1081344  ([B,H,S,NB,DK])
//  fQs   : 524288               @ 1605632
//  fKm   : 524288               @ 2129920  ([B,H,NB,S,DK])
//  fKs   : 524288               @ 2654208
//  mctx  : 131072               @ 3178496  ([B,S,D])
//  cctx  : 131072               @ 3309568
//  wmT   : 262144               @ 3440640  (mean_w transposed)
//  wcT   : 262144               @ 3702784
//  total : 3964928 floats = 15.86 MB
// ---------------------------------------------------------------------------

// ① split-K GEMM: out[o][m,d'] += sum_{k in slice} A1[m,k]W1[k,d'] + A2[m,k]W2[k,d']
//   grid.x = rowtile(16) | strip(2) | kslice(4) = 128 ; grid.y = o(6)
//   NOTE: no elu here — q2/k2/v2 are raw sums; elu applied downstream (k_fuse).
__global__ __launch_bounds__(256) void k_proj(
    const float* __restrict__ x_m, const float* __restrict__ x_c,
    const float* __restrict__ b_m, const float* __restrict__ b_c,
    const float* __restrict__ W_xm, const float* __restrict__ W_xc,
    const float* __restrict__ W_bm, const float* __restrict__ W_bc,
    float* __restrict__ qkv)
{
    const int o = blockIdx.y;                  // 0..5
    const int rowtile = blockIdx.x & 15;       // 16 tiles x 16 rows
    const int strip = (blockIdx.x >> 4) & 1;   // 256-col halves
    const int ks = blockIdx.x >> 5;            // 0..3 k-slices of 128
    const int t = threadIdx.x;
    const int dp = strip * 256 + t;
    const int m0 = rowtile * 16;
    const int kbase = ks * 128;

    const float* A1 = (o < 3) ? x_m : x_c;
    const float* A2 = (o < 3) ? b_m : b_c;
    const float* W1 = ((o < 3) ? W_xm : W_xc) + (o % 3) * (D_ * D_);
    const float* W2 = ((o < 3) ? W_bm : W_bc) + (o % 3) * (D_ * D_);

    __shared__ float a1[16][64];
    __shared__ float a2[16][64];

    float acc[16];
#pragma unroll
    for (int r = 0; r < 16; ++r) acc[r] = 0.f;

    for (int k0 = kbase; k0 < kbase + 128; k0 += 64) {
        __syncthreads();
#pragma unroll
        for (int u = 0; u < 4; ++u) {
            int e = u * 256 + t;
            int r = e >> 6, kk = e & 63;
            a1[r][kk] = A1[(m0 + r) * D_ + k0 + kk];
            a2[r][kk] = A2[(m0 + r) * D_ + k0 + kk];
        }
        __syncthreads();
        const float* w1p = W1 + k0 * D_ + dp;
        const float* w2p = W2 + k0 * D_ + dp;
#pragma unroll 8
        for (int kk = 0; kk < 64; ++kk) {
            float w1 = w1p[kk * D_];
            float w2 = w2p[kk * D_];
#pragma unroll
            for (int r = 0; r < 16; ++r)
                acc[r] = fmaf(a1[r][kk], w1, fmaf(a2[r][kk], w2, acc[r]));
        }
    }

    float* dst = qkv + o * (M_ * D_);
#pragma unroll
    for (int r = 0; r < 16; ++r)
        atomicAdd(&dst[(m0 + r) * D_ + dp], acc[r]);
}

// ② per-head 128x128 lins: pq=lin(pm,Wq2), pk=lin(pm,Wk2), bbq=lin(bbm,Wq1), bbk=lin(bbm,Wk1)
__global__ __launch_bounds__(128) void k_lin(
    const float* __restrict__ p_m, const float* __restrict__ bb_m,
    const float* __restrict__ Wq2, const float* __restrict__ bq2,
    const float* __restrict__ Wk2, const float* __restrict__ bk2,
    const float* __restrict__ Wq1, const float* __restrict__ bq1,
    const float* __restrict__ Wk1, const float* __restrict__ bk1,
    float* __restrict__ pq, float* __restrict__ pk,
    float* __restrict__ bbq, float* __restrict__ bbk)
{
    const int bx = blockIdx.x, t = threadIdx.x;
    const float *src, *Wm, *bias;
    float* dst;
    int row0;
    if (bx < 128)      { src = p_m;  Wm = Wq2; bias = bq2; dst = pq;  row0 = bx * 8; }
    else if (bx < 256) { src = p_m;  Wm = Wk2; bias = bk2; dst = pk;  row0 = (bx - 128) * 8; }
    else if (bx < 272) { src = bb_m; Wm = Wq1; bias = bq1; dst = bbq; row0 = (bx - 256) * 8; }
    else               { src = bb_m; Wm = Wk1; bias = bk1; dst = bbk; row0 = (bx - 272) * 8; }

    __shared__ float ps[8][128];
    __shared__ float wsh[128][33];

#pragma unroll
    for (int r = 0; r < 8; ++r) ps[r][t] = src[(row0 + r) * 128 + t];

    float acc[8];
#pragma unroll
    for (int r = 0; r < 8; ++r) acc[r] = 0.f;

    const int kc = t & 31, kr0 = t >> 5;
    for (int c0 = 0; c0 < 128; c0 += 32) {
        __syncthreads();
#pragma unroll 8
        for (int u = 0; u < 32; ++u)
            wsh[kr0 + u * 4][kc] = Wm[(kr0 + u * 4) * 128 + c0 + kc];
        __syncthreads();
#pragma unroll 8
        for (int k2 = 0; k2 < 32; ++k2) {
            float wv = wsh[t][k2];
#pragma unroll
            for (int r = 0; r < 8; ++r)
                acc[r] = fmaf(ps[r][c0 + k2], wv, acc[r]);
        }
    }

    float bv = bias[t];
#pragma unroll
    for (int r = 0; r < 8; ++r) dst[(row0 + r) * 128 + t] = acc[r] + bv;
}

// ③ transpose mean_w/cov_w (512x512), z selects matrix
__global__ __launch_bounds__(256) void k_transpose(
    const float* __restrict__ mean_w, const float* __restrict__ cov_w,
    float* __restrict__ wmT, float* __restrict__ wcT)
{
    const float* src = blockIdx.z ? cov_w : mean_w;
    float* dst = blockIdx.z ? wcT : wmT;
    __shared__ float tile[32][33];
    const int tx = threadIdx.x & 31, ty = threadIdx.x >> 5;
    const int bx = blockIdx.x, by = blockIdx.y;
#pragma unroll
    for (int u = 0; u < 4; ++u)
        tile[ty + u * 8][tx] = src[(by * 32 + ty + u * 8) * 512 + bx * 32 + tx];
    __syncthreads();
#pragma unroll
    for (int u = 0; u < 4; ++u)
        dst[(bx * 32 + ty + u * 8) * 512 + by * 32 + tx] = tile[tx][ty + u * 8];
}

// ④ tri-SAGP fuse: side=0 → fQ(i, sj); side=1 → fK(si, j).
//   elu+1 applied here to raw q2/k2 (c1). Side-0 also applies elu in-place to
//   v2 (qkv[5]) — each side-0 thread owns exactly one [B,S,D] element.
__global__ __launch_bounds__(128) void k_fuse(
    float* __restrict__ qkv, const float* __restrict__ pq,
    const float* __restrict__ pk, const float* __restrict__ bbq,
    const float* __restrict__ bbk, const float* __restrict__ bb_c,
    const float* __restrict__ p_c, const int* __restrict__ b_seq,
    float* __restrict__ fQm, float* __restrict__ fQs,
    float* __restrict__ fKm, float* __restrict__ fKs)
{
    const int t = threadIdx.x;
    const int ij = blockIdx.x;      // i (side 0) or j (side 1)
    const int h = blockIdx.y;
    const int b = blockIdx.z >> 1;
    const int side = blockIdx.z & 1;
    const int d = h * 128 + t;
    const float eps = 1e-24f;
    const int base = (b * S_ + ij) * D_ + d;
    const int s_self = b_seq[b * S_ + ij];

    float m1, c1, m3;
    if (side == 0) {
        m1 = qkv[base];
        c1 = elu1(qkv[3 * M_ * D_ + base]);
        m3 = pq[base];
        // in-place elu for v2
        int vi = 5 * M_ * D_ + base;
        qkv[vi] = elu1(qkv[vi]);
    } else {
        m1 = qkv[M_ * D_ + base];
        c1 = elu1(qkv[4 * M_ * D_ + base]);
        m3 = pk[base];
    }
    float c3 = p_c[base];

    float p1 = 1.f / fmaxf(c1, eps);
    float p3 = 1.f / fmaxf(c3, eps);
    float mp13 = m1 * p1 + m3 * p3;
    const float* bbM = side ? bbk : bbq;

#pragma unroll
    for (int sv = 0; sv < 4; ++sv) {
        int n1 = side ? s_self : sv;   // table first index = seq[j]
        int n2 = side ? sv : s_self;   // table second index = seq[i]
        int idx = (b * 16 + n1 * 4 + n2) * 512 + d;
        float m2 = bbM[idx];
        float c2 = bb_c[idx];
        float p2 = 1.f / fmaxf(c2, eps);
        float cc = 1.f / (p1 + p2 + p3);
        float fm = cc * (mp13 + m2 * p2);
        float fs = sqrtf(fmaxf(cc, eps));
        if (side == 0) {
            int o = ((b * H_ + h) * S_ + ij) * 512 + sv * 128 + t;   // [B,H,S,NB,DK]
            fQm[o] = fm; fQs[o] = fs;
        } else {
            int o = (((b * H_ + h) * 4 + sv) * S_ + ij) * 128 + t;   // [B,H,NB,S,DK]
            fKm[o] = fm; fKs[o] = fs;
        }
    }
}

// ⑤ per (b,h,i): W2 distances, softmax, probs out, mean/cov ctx
__global__ __launch_bounds__(128) void k_attn(
    const float* __restrict__ fQm, const float* __restrict__ fQs,
    const float* __restrict__ fKm, const float* __restrict__ fKs,
    const float* __restrict__ qkv, const int* __restrict__ b_seq,
    float* __restrict__ probs_out, float* __restrict__ mctx,
    float* __restrict__ cctx)
{
    const int t = threadIdx.x;     // j, later k
    const int i = blockIdx.x, h = blockIdx.y, b = blockIdx.z;

    __shared__ __attribute__((aligned(16))) float qm[4 * 132];
    __shared__ __attribute__((aligned(16))) float qs[4 * 132];
    __shared__ float red[4];
    __shared__ float pr[128], pr2[128];

    const int si = b_seq[b * S_ + i];
    const int sj = b_seq[b * S_ + t];
    const int qbase = ((b * H_ + h) * S_ + i) * 512;
#pragma unroll
    for (int u = 0; u < 4; ++u) {
        qm[u * 132 + t] = fQm[qbase + u * 128 + t];
        qs[u * 132 + t] = fQs[qbase + u * 128 + t];
    }
    __syncthreads();

    const int krow = (((b * H_ + h) * 4 + si) * S_ + t) * 128;
    const float4* kmp = (const float4*)(fKm + krow);
    const float4* ksp = (const float4*)(fKs + krow);

    float w2 = 0.f;
#pragma unroll 4
    for (int k4 = 0; k4 < 32; ++k4) {
        float4 km = kmp[k4];
        float4 ks = ksp[k4];
        float4 m = *(const float4*)&qm[sj * 132 + k4 * 4];
        float4 s = *(const float4*)&qs[sj * 132 + k4 * 4];
        float d0 = m.x - km.x, d1 = m.y - km.y, d2 = m.z - km.z, d3 = m.w - km.w;
        float e0 = s.x - ks.x, e1 = s.y - ks.y, e2 = s.z - ks.z, e3 = s.w - ks.w;
        w2 += d0 * d0 + d1 * d1 + d2 * d2 + d3 * d3
            + e0 * e0 + e1 * e1 + e2 * e2 + e3 * e3;
    }
    float score = -w2 * 0.08838834764831845f;  // 1/sqrt(128)

    // softmax over 128 threads (2 waves)
    float mx = score;
#pragma unroll
    for (int off = 32; off >= 1; off >>= 1) mx = fmaxf(mx, __shfl_xor(mx, off));
    if ((t & 63) == 0) red[t >> 6] = mx;
    __syncthreads();
    mx = fmaxf(red[0], red[1]);
    float e = __expf(score - mx);
    float sm = e;
#pragma unroll
    for (int off = 32; off >= 1; off >>= 1) sm += __shfl_xor(sm, off);
    if ((t & 63) == 0) red[2 + (t >> 6)] = sm;
    __syncthreads();
    float p = e / (red[2] + red[3]);

    probs_out[((b * H_ + h) * S_ + i) * S_ + t] = p;
    pr[t] = p;
    pr2[t] = p * p;
    __syncthreads();

    // ctx: thread t = k
    const float* v1 = qkv + 2 * M_ * D_ + (b * S_) * D_ + h * 128 + t;
    const float* v2 = qkv + 5 * M_ * D_ + (b * S_) * D_ + h * 128 + t;
    float am = 0.f, ac = 0.f;
#pragma unroll 8
    for (int j = 0; j < 128; ++j) {
        am = fmaf(pr[j], v1[j * D_], am);
        ac = fmaf(pr2[j], v2[j * D_], ac);
    }
    mctx[(b * S_ + i) * D_ + h * 128 + t] = am;
    cctx[(b * S_ + i) * D_ + h * 128 + t] = ac;
}

// ⑥ epilogue: y = ctx @ W^T + bias + residual; LN; write mean_h / cov_h
__global__ __launch_bounds__(256) void k_final(
    const float* __restrict__ mctx, const float* __restrict__ cctx,
    const float* __restrict__ wmT, const float* __restrict__ wcT,
    const float* __restrict__ mean_b, const float* __restrict__ cov_b,
    const float* __restrict__ x_m, const float* __restrict__ x_c,
    const float* __restrict__ ln_w, const float* __restrict__ ln_b,
    float* __restrict__ out)
{
    const int t = threadIdx.x;
    const int r0 = blockIdx.x * 2;
    const int d0 = t, d1 = t + 256;

    __shared__ float cm[2][512], ccv[2][512];
    __shared__ float red[8];

#pragma unroll
    for (int u = 0; u < 4; ++u) {
        int e = u * 256 + t;
        int r = e >> 9, dd = e & 511;
        cm[r][dd] = mctx[(r0 + r) * 512 + dd];
        ccv[r][dd] = cctx[(r0 + r) * 512 + dd];
    }
    __syncthreads();

    float am[2][2] = {{0.f, 0.f}, {0.f, 0.f}};
    float av[2][2] = {{0.f, 0.f}, {0.f, 0.f}};
#pragma unroll 4
    for (int d = 0; d < 512; ++d) {
        float w0 = wmT[d * 512 + d0], w1 = wmT[d * 512 + d1];
        float v0 = wcT[d * 512 + d0], v1 = wcT[d * 512 + d1];
        float a0 = cm[0][d], a1 = cm[1][d];
        float b0 = ccv[0][d], b1 = ccv[1][d];
        am[0][0] = fmaf(a0, w0, am[0][0]); am[0][1] = fmaf(a0, w1, am[0][1]);
        am[1][0] = fmaf(a1, w0, am[1][0]); am[1][1] = fmaf(a1, w1, am[1][1]);
        av[0][0] = fmaf(b0, v0, av[0][0]); av[0][1] = fmaf(b0, v1, av[0][1]);
        av[1][0] = fmaf(b1, v0, av[1][0]); av[1][1] = fmaf(b1, v1, av[1][1]);
    }

    const float lw0 = ln_w[d0], lw1 = ln_w[d1], lb0 = ln_b[d0], lb1 = ln_b[d1];

#pragma unroll
    for (int r = 0; r < 2; ++r) {
        const int row = r0 + r;
        {
            float y0 = am[r][0] + mean_b[d0] + x_m[row * 512 + d0];
            float y1 = am[r][1] + mean_b[d1] + x_m[row * 512 + d1];
            float s = y0 + y1, ss = y0 * y0 + y1 * y1;
#pragma unroll
            for (int off = 32; off >= 1; off >>= 1) { s += __shfl_xor(s, off); ss += __shfl_xor(ss, off); }
            if ((t & 63) == 0) { red[t >> 6] = s; red[4 + (t >> 6)] = ss; }
            __syncthreads();
            float mu = (red[0] + red[1] + red[2] + red[3]) * (1.f / 512.f);
            float var = (red[4] + red[5] + red[6] + red[7]) * (1.f / 512.f) - mu * mu;
            float rstd = 1.f / sqrtf(var + 1e-12f);
            out[row * 512 + d0] = (y0 - mu) * rstd * lw0 + lb0;
            out[row * 512 + d1] = (y1 - mu) * rstd * lw1 + lb1;
            __syncthreads();
        }
        {
            float y0 = av[r][0] + cov_b[d0] + x_c[row * 512 + d0];
            float y1 = av[r][1] + cov_b[d1] + x_c[row * 512 + d1];
            float s = y0 + y1, ss = y0 * y0 + y1 * y1;
#pragma unroll
            for (int off = 32; off >= 1; off >>= 1) { s += __shfl_xor(s, off); ss += __shfl_xor(ss, off); }
            if ((t & 63) == 0) { red[t >> 6] = s; red[4 + (t >> 6)] = ss; }
            __syncthreads();
            float mu = (red[0] + red[1] + red[2] + red[3]) * (1.f / 512.f);
            float var = (red[4] + red[5] + red[6] + red[7]) * (1.f / 512.f) - mu * mu;
            float rstd = 1.f / sqrtf(var + 1e-12f);
            out[131072 + row * 512 + d0] = (y0 - mu) * rstd * lw0 + lb0;
            out[131072 + row * 512 + d1] = (y1 - mu) * rstd * lw1 + lb1;
            __syncthreads();
        }
    }
}

extern "C" void kernel_launch(void* const* d_in, const int* in_sizes, int n_in,
                              void* d_out, int out_size, void* d_ws, size_t ws_size,
                              hipStream_t stream) {
    (void)in_sizes; (void)n_in; (void)out_size; (void)ws_size;
    const float* x_m   = (const float*)d_in[0];
    const float* x_c   = (const float*)d_in[1];
    const float* b_m   = (const float*)d_in[2];
    const float* b_c   = (const float*)d_in[3];
    const float* bb_m  = (const float*)d_in[4];
    const float* bb_c  = (const float*)d_in[5];
    const float* p_m   = (const float*)d_in[6];
    const float* p_c   = (const float*)d_in[7];
    const float* W_xm  = (const float*)d_in[8];
    const float* W_xc  = (const float*)d_in[9];
    const float* W_bm  = (const float*)d_in[10];
    const float* W_bc  = (const float*)d_in[11];
    const float* Wq1_w = (const float*)d_in[12];
    const float* Wq1_b = (const float*)d_in[13];
    const float* Wq2_w = (const float*)d_in[14];
    const float* Wq2_b = (const float*)d_in[15];
    const float* Wk1_w = (const float*)d_in[16];
    const float* Wk1_b = (const float*)d_in[17];
    const float* Wk2_w = (const float*)d_in[18];
    const float* Wk2_b = (const float*)d_in[19];
    const float* mean_w = (const float*)d_in[20];
    const float* mean_b = (const float*)d_in[21];
    const float* cov_w  = (const float*)d_in[22];
    const float* cov_b  = (const float*)d_in[23];
    const float* ln_w   = (const float*)d_in[24];
    const float* ln_b   = (const float*)d_in[25];
    const int*   b_seq  = (const int*)d_in[26];

    float* ws   = (float*)d_ws;
    float* qkv  = ws;
    float* pq   = ws + 786432;
    float* pk   = ws + 917504;
    float* bbq  = ws + 1048576;
    float* bbk  = ws + 1064960;
    float* fQm  = ws + 1081344;
    float* fQs  = ws + 1605632;
    float* fKm  = ws + 2129920;
    float* fKs  = ws + 2654208;
    float* mctx = ws + 3178496;
    float* cctx = ws + 3309568;
    float* wmT  = ws + 3440640;
    float* wcT  = ws + 3702784;
    float* out  = (float*)d_out;

    hipMemsetAsync(qkv, 0, 786432 * sizeof(float), stream);
    k_proj<<<dim3(128, 6), 256, 0, stream>>>(x_m, x_c, b_m, b_c, W_xm, W_xc, W_bm, W_bc, qkv);
    k_lin<<<dim3(288), 128, 0, stream>>>(p_m, bb_m, Wq2_w, Wq2_b, Wk2_w, Wk2_b,
                                         Wq1_w, Wq1_b, Wk1_w, Wk1_b, pq, pk, bbq, bbk);
    k_transpose<<<dim3(16, 16, 2), 256, 0, stream>>>(mean_w, cov_w, wmT, wcT);
    k_fuse<<<dim3(128, 4, 4), 128, 0, stream>>>(qkv, pq, pk, bbq, bbk, bb_c, p_c, b_seq,
                                                fQm, fQs, fKm, fKs);
    k_attn<<<dim3(128, 4, 2), 128, 0, stream>>>(fQm, fQs, fKm, fKs, qkv, b_seq,
                                                out + 262144, mctx, cctx);
    k_final<<<dim3(128), 256, 0, stream>>>(mctx, cctx, wmT, wcT, mean_b, cov_b,
                                           x_m, x_c, ln_w, ln_b, out);
}

// Round 3
// 193.743 us; speedup vs baseline: 1.9984x; 1.5999x over previous
//
#include <hip/hip_runtime.h>
#include <math.h>

#define B_ 2
#define S_ 128
#define H_ 4
#define DK_ 128
#define NB_ 4
#define D_ 512
#define M_ 256   // B_*S_

typedef __attribute__((ext_vector_type(8))) short short8;
typedef __attribute__((ext_vector_type(4))) float float4v;

__device__ __forceinline__ float elu1(float x) {
    return (x > 0.f) ? (x + 1.f) : __expf(x);
}

// round-to-nearest-even float -> bf16 bits
__device__ __forceinline__ unsigned short f2bf(float f) {
    unsigned u = __float_as_uint(f);
    unsigned r = (u + 0x7FFFu + ((u >> 16) & 1u)) >> 16;
    return (unsigned short)r;
}

// ---------------------------------------------------------------------------
// ws layout (float offsets)
//  qkv    : 786432   @ 0        (q1,k1,v1,q2,k2,v2 each [256,512]; o>=3 elu'd)
//  pq     : 131072   @ 786432
//  pk     : 131072   @ 917504
//  bbq    : 16384    @ 1048576
//  bbk    : 16384    @ 1064960
//  fQm    : 524288   @ 1081344  ([B,H,S,NB,DK])
//  fQs    : 524288   @ 1605632
//  fKm    : 524288   @ 2129920  ([B,H,NB,S,DK])
//  fKs    : 524288   @ 2654208
//  y_m    : 131072   @ 3178496  (epilogue GEMM fp32 partials, atomically accumulated)
//  y_c    : 131072   @ 3309568
//  A_m    : 131072   @ 3440640  (bf16 [256][1024] as shorts)
//  A_c    : 131072   @ 3571712
//  Wt     : 1572864  @ 3702784  (bf16 [6][512][1024], n-major)
//  wm_bf  : 131072   @ 5275648  (bf16 [512][512], [n][k] as given)
//  wc_bf  : 131072   @ 5406720
//  mctxb  : 65536    @ 5537792  (bf16 [256][512])
//  cctxb  : 65536    @ 5603328
//  total  : 5668864 floats = 22.7 MB
// ---------------------------------------------------------------------------

// ① elementwise fp32->bf16: job 0: A_m=[x_m|b_m], 1: A_c=[x_c|b_c], 2: wm, 3: wc
__global__ __launch_bounds__(256) void k_cvt_copy(
    const float* __restrict__ x_m, const float* __restrict__ b_m,
    const float* __restrict__ x_c, const float* __restrict__ b_c,
    const float* __restrict__ mean_w, const float* __restrict__ cov_w,
    unsigned short* __restrict__ A_m, unsigned short* __restrict__ A_c,
    unsigned short* __restrict__ wm_bf, unsigned short* __restrict__ wc_bf)
{
    const int t = threadIdx.x, job = blockIdx.y;
#pragma unroll
    for (int u = 0; u < 4; ++u) {
        int e = blockIdx.x * 1024 + u * 256 + t;   // 0..262143
        float v;
        unsigned short* dst;
        if (job == 0) {
            int m = e >> 10, k = e & 1023;
            v = (k < 512) ? x_m[m * 512 + k] : b_m[m * 512 + k - 512];
            dst = A_m;
        } else if (job == 1) {
            int m = e >> 10, k = e & 1023;
            v = (k < 512) ? x_c[m * 512 + k] : b_c[m * 512 + k - 512];
            dst = A_c;
        } else if (job == 2) { v = mean_w[e]; dst = wm_bf; }
        else                 { v = cov_w[e];  dst = wc_bf; }
        dst[e] = f2bf(v);
    }
}

// ② transpose+convert projection weights into Wt[o][n][k] bf16 (k-contig).
//    z = o*2+part; part 0 = W_x (k 0..511), part 1 = W_b (k 512..1023)
__global__ __launch_bounds__(256) void k_cvt_wt(
    const float* __restrict__ W_xm, const float* __restrict__ W_xc,
    const float* __restrict__ W_bm, const float* __restrict__ W_bc,
    unsigned short* __restrict__ Wt)
{
    const int o = blockIdx.z >> 1, part = blockIdx.z & 1;
    const float* src;
    if (part == 0) src = (o < 3) ? (W_xm + o * 262144) : (W_xc + (o - 3) * 262144);
    else           src = (o < 3) ? (W_bm + o * 262144) : (W_bc + (o - 3) * 262144);

    __shared__ unsigned short tile[32][33];
    const int tx = threadIdx.x & 31, ty = threadIdx.x >> 5;
    const int nt = blockIdx.x, kt = blockIdx.y;
#pragma unroll
    for (int u = 0; u < 4; ++u)
        tile[ty + u * 8][tx] = f2bf(src[(kt * 32 + ty + u * 8) * 512 + nt * 32 + tx]);
    __syncthreads();
    unsigned short* dst = Wt + o * 524288 + part * 512;
#pragma unroll
    for (int u = 0; u < 4; ++u)
        dst[(nt * 32 + ty + u * 8) * 1024 + kt * 32 + tx] = tile[tx][ty + u * 8];
}

// ③ MFMA projection GEMM: qkv[o][m][n] = sum_k A[m][k]*Wt[o][n][k]; elu for o>=3.
//    One wave per 16x16 C-tile; 3072 waves total; K=1024 (32 mfma, 2 accs).
__global__ __launch_bounds__(256) void k_mm(
    const unsigned short* __restrict__ A_m, const unsigned short* __restrict__ A_c,
    const unsigned short* __restrict__ Wt, float* __restrict__ qkv)
{
    const int t = threadIdx.x;
    const int wid = blockIdx.x * 4 + (t >> 6);
    const int lane = t & 63;
    const int o = wid >> 9;            // 0..5
    const int rem = wid & 511;
    const int nt = rem & 31, mt = rem >> 5;
    const int m0 = mt * 16, n0 = nt * 16;
    const int l15 = lane & 15, quad = lane >> 4;

    const unsigned short* A = (o < 3) ? A_m : A_c;
    const unsigned short* ap = A + (m0 + l15) * 1024 + quad * 8;
    const unsigned short* bp = Wt + o * 524288 + (n0 + l15) * 1024 + quad * 8;

    float4v acc0 = {0.f, 0.f, 0.f, 0.f};
    float4v acc1 = {0.f, 0.f, 0.f, 0.f};
#pragma unroll
    for (int k0 = 0; k0 < 1024; k0 += 64) {
        short8 a0 = *(const short8*)(ap + k0);
        short8 b0 = *(const short8*)(bp + k0);
        short8 a1 = *(const short8*)(ap + k0 + 32);
        short8 b1 = *(const short8*)(bp + k0 + 32);
        acc0 = __builtin_amdgcn_mfma_f32_16x16x32_bf16(a0, b0, acc0, 0, 0, 0);
        acc1 = __builtin_amdgcn_mfma_f32_16x16x32_bf16(a1, b1, acc1, 0, 0, 0);
    }

    float* dst = qkv + o * 131072;
#pragma unroll
    for (int r = 0; r < 4; ++r) {
        float v = acc0[r] + acc1[r];
        if (o >= 3) v = elu1(v);
        dst[(m0 + quad * 4 + r) * 512 + n0 + l15] = v;
    }
}

// ④ per-head 128x128 lins (unchanged, fp32)
__global__ __launch_bounds__(128) void k_lin(
    const float* __restrict__ p_m, const float* __restrict__ bb_m,
    const float* __restrict__ Wq2, const float* __restrict__ bq2,
    const float* __restrict__ Wk2, const float* __restrict__ bk2,
    const float* __restrict__ Wq1, const float* __restrict__ bq1,
    const float* __restrict__ Wk1, const float* __restrict__ bk1,
    float* __restrict__ pq, float* __restrict__ pk,
    float* __restrict__ bbq, float* __restrict__ bbk)
{
    const int bx = blockIdx.x, t = threadIdx.x;
    const float *src, *Wm, *bias;
    float* dst;
    int row0;
    if (bx < 128)      { src = p_m;  Wm = Wq2; bias = bq2; dst = pq;  row0 = bx * 8; }
    else if (bx < 256) { src = p_m;  Wm = Wk2; bias = bk2; dst = pk;  row0 = (bx - 128) * 8; }
    else if (bx < 272) { src = bb_m; Wm = Wq1; bias = bq1; dst = bbq; row0 = (bx - 256) * 8; }
    else               { src = bb_m; Wm = Wk1; bias = bk1; dst = bbk; row0 = (bx - 272) * 8; }

    __shared__ float ps[8][128];
    __shared__ float wsh[128][33];

#pragma unroll
    for (int r = 0; r < 8; ++r) ps[r][t] = src[(row0 + r) * 128 + t];

    float acc[8];
#pragma unroll
    for (int r = 0; r < 8; ++r) acc[r] = 0.f;

    const int kc = t & 31, kr0 = t >> 5;
    for (int c0 = 0; c0 < 128; c0 += 32) {
        __syncthreads();
#pragma unroll 8
        for (int u = 0; u < 32; ++u)
            wsh[kr0 + u * 4][kc] = Wm[(kr0 + u * 4) * 128 + c0 + kc];
        __syncthreads();
#pragma unroll 8
        for (int k2 = 0; k2 < 32; ++k2) {
            float wv = wsh[t][k2];
#pragma unroll
            for (int r = 0; r < 8; ++r)
                acc[r] = fmaf(ps[r][c0 + k2], wv, acc[r]);
        }
    }

    float bv = bias[t];
#pragma unroll
    for (int r = 0; r < 8; ++r) dst[(row0 + r) * 128 + t] = acc[r] + bv;
}

// ⑤ tri-SAGP fuse (q2/k2/v2 already elu'd by k_mm)
__global__ __launch_bounds__(128) void k_fuse(
    const float* __restrict__ qkv, const float* __restrict__ pq,
    const float* __restrict__ pk, const float* __restrict__ bbq,
    const float* __restrict__ bbk, const float* __restrict__ bb_c,
    const float* __restrict__ p_c, const int* __restrict__ b_seq,
    float* __restrict__ fQm, float* __restrict__ fQs,
    float* __restrict__ fKm, float* __restrict__ fKs)
{
    const int t = threadIdx.x;
    const int ij = blockIdx.x;
    const int h = blockIdx.y;
    const int b = blockIdx.z >> 1;
    const int side = blockIdx.z & 1;
    const int d = h * 128 + t;
    const float eps = 1e-24f;
    const int base = (b * S_ + ij) * D_ + d;
    const int s_self = b_seq[b * S_ + ij];

    float m1, c1, m3;
    if (side == 0) { m1 = qkv[base];           c1 = qkv[3 * M_ * D_ + base]; m3 = pq[base]; }
    else           { m1 = qkv[M_ * D_ + base]; c1 = qkv[4 * M_ * D_ + base]; m3 = pk[base]; }
    float c3 = p_c[base];

    float p1 = 1.f / fmaxf(c1, eps);
    float p3 = 1.f / fmaxf(c3, eps);
    float mp13 = m1 * p1 + m3 * p3;
    const float* bbM = side ? bbk : bbq;

#pragma unroll
    for (int sv = 0; sv < 4; ++sv) {
        int n1 = side ? s_self : sv;
        int n2 = side ? sv : s_self;
        int idx = (b * 16 + n1 * 4 + n2) * 512 + d;
        float m2 = bbM[idx];
        float c2 = bb_c[idx];
        float p2 = 1.f / fmaxf(c2, eps);
        float cc = 1.f / (p1 + p2 + p3);
        float fm = cc * (mp13 + m2 * p2);
        float fs = sqrtf(fmaxf(cc, eps));
        if (side == 0) {
            int o = ((b * H_ + h) * S_ + ij) * 512 + sv * 128 + t;
            fQm[o] = fm; fQs[o] = fs;
        } else {
            int o = (((b * H_ + h) * 4 + sv) * S_ + ij) * 128 + t;
            fKm[o] = fm; fKs[o] = fs;
        }
    }
}

// ⑥ per (b,h,i): W2 distances, softmax, probs out, mean/cov ctx (bf16 out)
__global__ __launch_bounds__(128) void k_attn(
    const float* __restrict__ fQm, const float* __restrict__ fQs,
    const float* __restrict__ fKm, const float* __restrict__ fKs,
    const float* __restrict__ qkv, const int* __restrict__ b_seq,
    float* __restrict__ probs_out, unsigned short* __restrict__ mctxb,
    unsigned short* __restrict__ cctxb)
{
    const int t = threadIdx.x;
    const int i = blockIdx.x, h = blockIdx.y, b = blockIdx.z;

    __shared__ __attribute__((aligned(16))) float qm[4 * 132];
    __shared__ __attribute__((aligned(16))) float qs[4 * 132];
    __shared__ float red[4];
    __shared__ float pr[128], pr2[128];

    const int si = b_seq[b * S_ + i];
    const int sj = b_seq[b * S_ + t];
    const int qbase = ((b * H_ + h) * S_ + i) * 512;
#pragma unroll
    for (int u = 0; u < 4; ++u) {
        qm[u * 132 + t] = fQm[qbase + u * 128 + t];
        qs[u * 132 + t] = fQs[qbase + u * 128 + t];
    }
    __syncthreads();

    const int krow = (((b * H_ + h) * 4 + si) * S_ + t) * 128;
    const float4* kmp = (const float4*)(fKm + krow);
    const float4* ksp = (const float4*)(fKs + krow);

    float w2 = 0.f;
#pragma unroll 4
    for (int k4 = 0; k4 < 32; ++k4) {
        float4 km = kmp[k4];
        float4 ks = ksp[k4];
        float4 m = *(const float4*)&qm[sj * 132 + k4 * 4];
        float4 s = *(const float4*)&qs[sj * 132 + k4 * 4];
        float d0 = m.x - km.x, d1 = m.y - km.y, d2 = m.z - km.z, d3 = m.w - km.w;
        float e0 = s.x - ks.x, e1 = s.y - ks.y, e2 = s.z - ks.z, e3 = s.w - ks.w;
        w2 += d0 * d0 + d1 * d1 + d2 * d2 + d3 * d3
            + e0 * e0 + e1 * e1 + e2 * e2 + e3 * e3;
    }
    float score = -w2 * 0.08838834764831845f;

    float mx = score;
#pragma unroll
    for (int off = 32; off >= 1; off >>= 1) mx = fmaxf(mx, __shfl_xor(mx, off));
    if ((t & 63) == 0) red[t >> 6] = mx;
    __syncthreads();
    mx = fmaxf(red[0], red[1]);
    float e = __expf(score - mx);
    float sm = e;
#pragma unroll
    for (int off = 32; off >= 1; off >>= 1) sm += __shfl_xor(sm, off);
    if ((t & 63) == 0) red[2 + (t >> 6)] = sm;
    __syncthreads();
    float p = e / (red[2] + red[3]);

    probs_out[((b * H_ + h) * S_ + i) * S_ + t] = p;
    pr[t] = p;
    pr2[t] = p * p;
    __syncthreads();

    const float* v1 = qkv + 2 * M_ * D_ + (b * S_) * D_ + h * 128 + t;
    const float* v2 = qkv + 5 * M_ * D_ + (b * S_) * D_ + h * 128 + t;
    float am = 0.f, ac = 0.f;
#pragma unroll 8
    for (int j = 0; j < 128; ++j) {
        am = fmaf(pr[j], v1[j * D_], am);
        ac = fmaf(pr2[j], v2[j * D_], ac);
    }
    mctxb[(b * S_ + i) * D_ + h * 128 + t] = f2bf(am);
    cctxb[(b * S_ + i) * D_ + h * 128 + t] = f2bf(ac);
}

// ⑦ MFMA epilogue GEMM: y[mat][m][n] += sum_k ctx_bf[m][k]*w_bf[n][k]
//    (mean_w/cov_w are [n][k] row-major already — k-contig, no transpose).
//    split-K x2, fp32 atomics into y_m/y_c. 2048 waves.
__global__ __launch_bounds__(256) void k_fin_mm(
    const unsigned short* __restrict__ mctxb, const unsigned short* __restrict__ cctxb,
    const unsigned short* __restrict__ wm_bf, const unsigned short* __restrict__ wc_bf,
    float* __restrict__ y_m, float* __restrict__ y_c)
{
    const int t = threadIdx.x;
    const int wid = blockIdx.x * 4 + (t >> 6);
    const int lane = t & 63;
    const int mat = wid >> 10;
    const int rem = wid & 1023;
    const int ks = rem >> 9;
    const int r2 = rem & 511;
    const int nt = r2 & 31, mt = r2 >> 5;
    const int m0 = mt * 16, n0 = nt * 16, kbase = ks * 256;
    const int l15 = lane & 15, quad = lane >> 4;

    const unsigned short* A = mat ? cctxb : mctxb;
    const unsigned short* Bw = mat ? wc_bf : wm_bf;
    float* y = mat ? y_c : y_m;

    const unsigned short* ap = A + (m0 + l15) * 512 + kbase + quad * 8;
    const unsigned short* bp = Bw + (n0 + l15) * 512 + kbase + quad * 8;

    float4v acc0 = {0.f, 0.f, 0.f, 0.f};
    float4v acc1 = {0.f, 0.f, 0.f, 0.f};
#pragma unroll
    for (int k0 = 0; k0 < 256; k0 += 64) {
        short8 a0 = *(const short8*)(ap + k0);
        short8 b0 = *(const short8*)(bp + k0);
        short8 a1 = *(const short8*)(ap + k0 + 32);
        short8 b1 = *(const short8*)(bp + k0 + 32);
        acc0 = __builtin_amdgcn_mfma_f32_16x16x32_bf16(a0, b0, acc0, 0, 0, 0);
        acc1 = __builtin_amdgcn_mfma_f32_16x16x32_bf16(a1, b1, acc1, 0, 0, 0);
    }
#pragma unroll
    for (int r = 0; r < 4; ++r)
        atomicAdd(&y[(m0 + quad * 4 + r) * 512 + n0 + l15], acc0[r] + acc1[r]);
}

// ⑧ bias + residual + LayerNorm -> out. One block per output row (512 rows).
__global__ __launch_bounds__(256) void k_ln(
    const float* __restrict__ y_m, const float* __restrict__ y_c,
    const float* __restrict__ mean_b, const float* __restrict__ cov_b,
    const float* __restrict__ x_m, const float* __restrict__ x_c,
    const float* __restrict__ ln_w, const float* __restrict__ ln_b,
    float* __restrict__ out)
{
    const int t = threadIdx.x;
    const int id = blockIdx.x;
    const int mat = id >> 8, row = id & 255;
    const float* yg = mat ? y_c : y_m;
    const float* bias = mat ? cov_b : mean_b;
    const float* res = mat ? x_c : x_m;
    const int base = row * 512;

    __shared__ float red[8];

    float y0 = yg[base + t] + bias[t] + res[base + t];
    float y1 = yg[base + 256 + t] + bias[256 + t] + res[base + 256 + t];
    float s = y0 + y1, ss = y0 * y0 + y1 * y1;
#pragma unroll
    for (int off = 32; off >= 1; off >>= 1) { s += __shfl_xor(s, off); ss += __shfl_xor(ss, off); }
    if ((t & 63) == 0) { red[t >> 6] = s; red[4 + (t >> 6)] = ss; }
    __syncthreads();
    float mu = (red[0] + red[1] + red[2] + red[3]) * (1.f / 512.f);
    float var = (red[4] + red[5] + red[6] + red[7]) * (1.f / 512.f) - mu * mu;
    float rstd = 1.f / sqrtf(var + 1e-12f);
    out[mat * 131072 + base + t] = (y0 - mu) * rstd * ln_w[t] + ln_b[t];
    out[mat * 131072 + base + 256 + t] = (y1 - mu) * rstd * ln_w[256 + t] + ln_b[256 + t];
}

extern "C" void kernel_launch(void* const* d_in, const int* in_sizes, int n_in,
                              void* d_out, int out_size, void* d_ws, size_t ws_size,
                              hipStream_t stream) {
    (void)in_sizes; (void)n_in; (void)out_size; (void)ws_size;
    const float* x_m   = (const float*)d_in[0];
    const float* x_c   = (const float*)d_in[1];
    const float* b_m   = (const float*)d_in[2];
    const float* b_c   = (const float*)d_in[3];
    const float* bb_m  = (const float*)d_in[4];
    const float* bb_c  = (const float*)d_in[5];
    const float* p_m   = (const float*)d_in[6];
    const float* p_c   = (const float*)d_in[7];
    const float* W_xm  = (const float*)d_in[8];
    const float* W_xc  = (const float*)d_in[9];
    const float* W_bm  = (const float*)d_in[10];
    const float* W_bc  = (const float*)d_in[11];
    const float* Wq1_w = (const float*)d_in[12];
    const float* Wq1_b = (const float*)d_in[13];
    const float* Wq2_w = (const float*)d_in[14];
    const float* Wq2_b = (const float*)d_in[15];
    const float* Wk1_w = (const float*)d_in[16];
    const float* Wk1_b = (const float*)d_in[17];
    const float* Wk2_w = (const float*)d_in[18];
    const float* Wk2_b = (const float*)d_in[19];
    const float* mean_w = (const float*)d_in[20];
    const float* mean_b = (const float*)d_in[21];
    const float* cov_w  = (const float*)d_in[22];
    const float* cov_b  = (const float*)d_in[23];
    const float* ln_w   = (const float*)d_in[24];
    const float* ln_b   = (const float*)d_in[25];
    const int*   b_seq  = (const int*)d_in[26];

    float* ws   = (float*)d_ws;
    float* qkv  = ws;
    float* pq   = ws + 786432;
    float* pk   = ws + 917504;
    float* bbq  = ws + 1048576;
    float* bbk  = ws + 1064960;
    float* fQm  = ws + 1081344;
    float* fQs  = ws + 1605632;
    float* fKm  = ws + 2129920;
    float* fKs  = ws + 2654208;
    float* y_m  = ws + 3178496;
    float* y_c  = ws + 3309568;
    unsigned short* A_m   = (unsigned short*)(ws + 3440640);
    unsigned short* A_c   = (unsigned short*)(ws + 3571712);
    unsigned short* Wt    = (unsigned short*)(ws + 3702784);
    unsigned short* wm_bf = (unsigned short*)(ws + 5275648);
    unsigned short* wc_bf = (unsigned short*)(ws + 5406720);
    unsigned short* mctxb = (unsigned short*)(ws + 5537792);
    unsigned short* cctxb = (unsigned short*)(ws + 5603328);
    float* out  = (float*)d_out;

    hipMemsetAsync(y_m, 0, 262144 * sizeof(float), stream);  // y_m + y_c contiguous
    k_cvt_copy<<<dim3(256, 4), 256, 0, stream>>>(x_m, b_m, x_c, b_c, mean_w, cov_w,
                                                 A_m, A_c, wm_bf, wc_bf);
    k_cvt_wt<<<dim3(16, 16, 12), 256, 0, stream>>>(W_xm, W_xc, W_bm, W_bc, Wt);
    k_mm<<<dim3(768), 256, 0, stream>>>(A_m, A_c, Wt, qkv);
    k_lin<<<dim3(288), 128, 0, stream>>>(p_m, bb_m, Wq2_w, Wq2_b, Wk2_w, Wk2_b,
                                         Wq1_w, Wq1_b, Wk1_w, Wk1_b, pq, pk, bbq, bbk);
    k_fuse<<<dim3(128, 4, 4), 128, 0, stream>>>(qkv, pq, pk, bbq, bbk, bb_c, p_c, b_seq,
                                                fQm, fQs, fKm, fKs);
    k_attn<<<dim3(128, 4, 2), 128, 0, stream>>>(fQm, fQs, fKm, fKs, qkv, b_seq,
                                                out + 262144, mctxb, cctxb);
    k_fin_mm<<<dim3(512), 256, 0, stream>>>(mctxb, cctxb, wm_bf, wc_bf, y_m, y_c);
    k_ln<<<dim3(512), 256, 0, stream>>>(y_m, y_c, mean_b, cov_b, x_m, x_c,
                                        ln_w, ln_b, out);
}